// Round 6
// baseline (460.091 us; speedup 1.0000x reference)
//
#include <hip/hip_runtime.h>

typedef __attribute__((ext_vector_type(8))) short short8;
typedef __attribute__((ext_vector_type(4))) float f32x4;

#define NODE_D 128
#define SCAN_T 256
#define SCAN_I 8
#define NPART 8
#define ECHUNK 8192        // edges per counting/scatter chunk

__device__ __forceinline__ float bf2f(ushort u) {
    union { uint i; float f; } c; c.i = ((uint)u) << 16; return c.f;
}
__device__ __forceinline__ ushort f2bf(float f) {
    union { float f; uint i; } c; c.f = f;
    return (ushort)((c.i + 0x7FFF + ((c.i >> 16) & 1)) >> 16);
}

// ---------- all 7 weight matrices f32 -> bf16, concatenated dst ----------
__global__ __launch_bounds__(256) void k_cvt_w(const float* __restrict__ s0, const float* __restrict__ s1,
                                               const float* __restrict__ s2, const float* __restrict__ s3,
                                               const float* __restrict__ s4, const float* __restrict__ s5,
                                               const float* __restrict__ s6, ushort* __restrict__ dst) {
    int i = blockIdx.x * 256 + threadIdx.x;
    if (i >= 98304) return;
    const float* s; int off;
    if (i < 16384)      { s = s0; off = i; }
    else if (i < 32768) { s = s1; off = i - 16384; }
    else if (i < 49152) { s = s2; off = i - 32768; }
    else if (i < 65536) { s = s3; off = i - 49152; }
    else if (i < 81920) { s = s4; off = i - 65536; }
    else if (i < 90112) { s = s5; off = i - 81920; }
    else                { s = s6; off = i - 90112; }
    dst[i] = f2bf(s[off]);
}

// ---------- degree histogram + per-chunk partition counts ----------
__global__ __launch_bounds__(256) void k_hist2(const int* __restrict__ dst,
                                               int* __restrict__ deg,
                                               int* __restrict__ cm,
                                               int E, int psz) {
    __shared__ int lh[NPART];
    if (threadIdx.x < NPART) lh[threadIdx.x] = 0;
    __syncthreads();
    int c = blockIdx.x;
    int lo = c * ECHUNK, hi = min(lo + ECHUNK, E);
    for (int i = lo + (int)threadIdx.x; i < hi; i += 256) {
        int d = dst[i];
        atomicAdd(&deg[d], 1);
        atomicAdd(&lh[d / psz], 1);
    }
    __syncthreads();
    if (threadIdx.x < NPART) cm[c * NPART + threadIdx.x] = lh[threadIdx.x];
}

// ---------- scan pass A ----------
__global__ __launch_bounds__(SCAN_T) void k_scan_bsum(const int* __restrict__ deg,
                                                      int* __restrict__ bsums, int n) {
    __shared__ int red[SCAN_T];
    int base = blockIdx.x * SCAN_T * SCAN_I + threadIdx.x * SCAN_I;
    int s = 0;
    #pragma unroll
    for (int i = 0; i < SCAN_I; ++i) {
        int idx = base + i;
        if (idx < n) s += deg[idx];
    }
    red[threadIdx.x] = s;
    __syncthreads();
    for (int st = SCAN_T / 2; st > 0; st >>= 1) {
        if (threadIdx.x < st) red[threadIdx.x] += red[threadIdx.x + st];
        __syncthreads();
    }
    if (threadIdx.x == 0) bsums[blockIdx.x] = red[0];
}

// ---------- scan pass B ----------
__global__ void k_scan_bsum_excl(int* __restrict__ bsums, int nb,
                                 int* __restrict__ rowptr_last) {
    if (blockIdx.x == 0 && threadIdx.x == 0) {
        int run = 0;
        for (int i = 0; i < nb; ++i) {
            int v = bsums[i];
            bsums[i] = run;
            run += v;
        }
        rowptr_last[0] = run;
    }
}

// ---------- scan pass C ----------
__global__ __launch_bounds__(SCAN_T) void k_scan_final(const int* __restrict__ deg,
                                                       const int* __restrict__ bsums,
                                                       int* __restrict__ rowptr,
                                                       int* __restrict__ cursor, int n) {
    __shared__ int ts[SCAN_T];
    int base = blockIdx.x * SCAN_T * SCAN_I + threadIdx.x * SCAN_I;
    int v[SCAN_I];
    int s = 0;
    #pragma unroll
    for (int i = 0; i < SCAN_I; ++i) {
        int idx = base + i;
        v[i] = (idx < n) ? deg[idx] : 0;
        s += v[i];
    }
    ts[threadIdx.x] = s;
    __syncthreads();
    for (int st = 1; st < SCAN_T; st <<= 1) {
        int add = (threadIdx.x >= st) ? ts[threadIdx.x - st] : 0;
        __syncthreads();
        ts[threadIdx.x] += add;
        __syncthreads();
    }
    int excl = (threadIdx.x == 0 ? 0 : ts[threadIdx.x - 1]) + bsums[blockIdx.x];
    #pragma unroll
    for (int i = 0; i < SCAN_I; ++i) {
        int idx = base + i;
        if (idx < n) { rowptr[idx] = excl; cursor[idx] = excl; }
        excl += v[i];
    }
}

// ---------- scan of chunk x partition matrix (partition-major), single block ----------
// elem e = p*NC + c  <->  cm[c*NPART+p]. Exclusive scan -> om; pbase[p] = partition base.
__global__ __launch_bounds__(256) void k_cmscan(const int* __restrict__ cm,
                                                int* __restrict__ om,
                                                int* __restrict__ pbase, int NC) {
    __shared__ int ts[256];
    int total = NC * NPART;
    int base = threadIdx.x * 8;
    int v[8];
    int s = 0;
    #pragma unroll
    for (int i = 0; i < 8; ++i) {
        int e = base + i;
        if (e < total) { int p = e / NC; int c = e - p * NC; v[i] = cm[c * NPART + p]; }
        else v[i] = 0;
        s += v[i];
    }
    ts[threadIdx.x] = s;
    __syncthreads();
    for (int st = 1; st < 256; st <<= 1) {
        int add = (threadIdx.x >= st) ? ts[threadIdx.x - st] : 0;
        __syncthreads();
        ts[threadIdx.x] += add;
        __syncthreads();
    }
    int excl = (threadIdx.x == 0 ? 0 : ts[threadIdx.x - 1]);
    #pragma unroll
    for (int i = 0; i < 8; ++i) {
        int e = base + i;
        if (e < total) {
            int p = e / NC; int c = e - p * NC;
            om[c * NPART + p] = excl;
            if (c == 0) pbase[p] = excl;
        }
        excl += v[i];
    }
    if (threadIdx.x == 255) pbase[NPART] = ts[255];
}

// ---------- deterministic scatter: chunk edges -> partition-major ebuf ----------
// No global atomics: per-chunk base offsets from cmscan; LDS cursors within chunk.
// Each (chunk,partition) run is ~E/NC/8 edges contiguous -> coalesced 8B writes.
__global__ __launch_bounds__(256) void k_scatter2(const int* __restrict__ src,
                                                  const int* __restrict__ dst,
                                                  const int* __restrict__ om,
                                                  uint2* __restrict__ ebuf,
                                                  int E, int psz) {
    __shared__ int cur[NPART];
    int c = blockIdx.x;
    if (threadIdx.x < NPART) cur[threadIdx.x] = om[c * NPART + threadIdx.x];
    __syncthreads();
    int lo = c * ECHUNK, hi = min(lo + ECHUNK, E);
    for (int i = lo + (int)threadIdx.x; i < hi; i += 256) {
        int d = dst[i];
        int pos = atomicAdd(&cur[d / psz], 1);
        uint2 e; e.x = (uint)src[i]; e.y = (uint)d;
        ebuf[pos] = e;
    }
}

// ---------- final CSR fill from partition-major ebuf ----------
// Partition p handled only by blocks with blockIdx&7==p (XCD-aligned under
// round-robin dispatch): col/cursor windows (~800KB/50KB) stay L2-resident and
// single-XCD; ebuf slice read exactly once.
__global__ __launch_bounds__(256) void k_fillq(const uint2* __restrict__ ebuf,
                                               const int* __restrict__ pbase,
                                               int* __restrict__ cursor,
                                               int* __restrict__ col) {
    int p = blockIdx.x & 7;
    int sb = blockIdx.x >> 3;
    int lo = pbase[p], hi = pbase[p + 1];
    int stride = (gridDim.x >> 3) * 256;
    for (int j = lo + sb * 256 + (int)threadIdx.x; j < hi; j += stride) {
        uint2 e = ebuf[j];
        int pos = atomicAdd(&cursor[e.y], 1);
        col[pos] = (int)e.x;
    }
}

// ---------- mean aggregation over bf16 activations: one wave per node ----------
template<int D>
__global__ __launch_bounds__(256) void k_aggb(const ushort* __restrict__ h,
                                              const int* __restrict__ rowptr,
                                              const int* __restrict__ col,
                                              ushort* __restrict__ mean, int N) {
    int node = blockIdx.x * 4 + (threadIdx.x >> 6);
    if (node >= N) return;
    int lane = threadIdx.x & 63;
    int beg = rowptr[node];
    int end = rowptr[node + 1];
    float inv = 1.f / fmaxf((float)(end - beg), 1.f);
    if constexpr (D == 128) {
        const ushort* base = h + lane * 2;
        float ax = 0.f, ay = 0.f;
        int j = beg;
        for (; j + 7 < end; j += 8) {
            uint v[8];
            #pragma unroll
            for (int q = 0; q < 8; ++q)
                v[q] = *(const uint*)(base + (size_t)col[j + q] * 128);
            #pragma unroll
            for (int q = 0; q < 8; ++q) {
                ax += bf2f((ushort)v[q]);
                ay += bf2f((ushort)(v[q] >> 16));
            }
        }
        for (; j < end; ++j) {
            uint v = *(const uint*)(base + (size_t)col[j] * 128);
            ax += bf2f((ushort)v);
            ay += bf2f((ushort)(v >> 16));
        }
        uint o = (uint)f2bf(ax * inv) | ((uint)f2bf(ay * inv) << 16);
        *(uint*)(mean + (size_t)node * 128 + lane * 2) = o;
    } else {
        const ushort* base = h + lane;
        float ax = 0.f;
        int j = beg;
        for (; j + 7 < end; j += 8) {
            ushort v[8];
            #pragma unroll
            for (int q = 0; q < 8; ++q) v[q] = base[(size_t)col[j + q] * D];
            #pragma unroll
            for (int q = 0; q < 8; ++q) ax += bf2f(v[q]);
        }
        for (; j < end; ++j) ax += bf2f(base[(size_t)col[j] * D]);
        mean[(size_t)node * D + lane] = f2bf(ax * inv);
    }
}

// ---------- MFMA dense: out = A@W0^T (+ A1@W1^T) [+bias] [+add] [+relu] ----------
// A0: [N][128] bf16 (or f32 if A0F32) row-major. W: [OD][128] bf16 row-major.
// Tile: 128 rows x OD cols, 4 waves. LDS [dim][64] bf16, XOR swizzle byte^=((row&7)<<4).
template<int OD, bool DUAL, bool HAS_ADD, bool RELU, bool OUT_F32, bool A0F32>
__global__ __launch_bounds__(256) void k_mm(const void* __restrict__ A0,
                                            const ushort* __restrict__ A1,
                                            const ushort* __restrict__ W0,
                                            const ushort* __restrict__ W1,
                                            const float* __restrict__ bias,
                                            const ushort* __restrict__ add,
                                            void* __restrict__ outp, int N) {
    constexpr int NK    = DUAL ? 4 : 2;
    constexpr int M_REP = (OD == 128) ? 4 : 2;
    constexpr int N_REP = 4;
    constexpr int WROWS = M_REP * 16;

    __shared__ __align__(16) ushort sA[128 * 64];
    __shared__ __align__(16) ushort sW[OD * 64];

    const int t    = threadIdx.x;
    const int wid  = t >> 6;
    const int lane = t & 63;
    const int l15  = lane & 15;
    const int lhi  = lane >> 4;
    const int r0   = blockIdx.x * 128;

    int wm, wn0;
    if (OD == 128) { wm = wid >> 1; wn0 = (wid & 1) * 64; }
    else           { wm = wid;      wn0 = 0; }

    f32x4 zero = {0.f, 0.f, 0.f, 0.f};
    f32x4 acc[M_REP][N_REP];
    #pragma unroll
    for (int m = 0; m < M_REP; ++m)
        #pragma unroll
        for (int n = 0; n < N_REP; ++n) acc[m][n] = zero;

    const ushort* A0b = (const ushort*)A0;
    const float*  A0f = (const float*)A0;

    for (int kc = 0; kc < NK; ++kc) {
        const ushort* Ws = (DUAL && kc >= 2) ? W1 : W0;
        const ushort* As = (DUAL && kc >= 2) ? A1 : A0b;
        const int kloc = (kc & 1) * 64;

        __syncthreads();
        // stage A tile: 128 rows x 64 k
        #pragma unroll
        for (int it = 0; it < 4; ++it) {
            int slot = it * 256 + t;
            int row = slot >> 3, k8 = slot & 7;
            int gr = r0 + row; if (gr >= N) gr = N - 1;
            short8 v;
            if constexpr (A0F32) {
                float4 p = *(const float4*)(A0f + (size_t)gr * 128 + kloc + k8 * 8);
                float4 q = *(const float4*)(A0f + (size_t)gr * 128 + kloc + k8 * 8 + 4);
                v[0] = (short)f2bf(p.x); v[1] = (short)f2bf(p.y);
                v[2] = (short)f2bf(p.z); v[3] = (short)f2bf(p.w);
                v[4] = (short)f2bf(q.x); v[5] = (short)f2bf(q.y);
                v[6] = (short)f2bf(q.z); v[7] = (short)f2bf(q.w);
            } else {
                v = *(const short8*)(As + (size_t)gr * 128 + kloc + k8 * 8);
            }
            *(short8*)((char*)sA + ((row * 128 + k8 * 16) ^ ((row & 7) << 4))) = v;
        }
        // stage W tile: OD rows x 64 k
        #pragma unroll
        for (int it = 0; it < OD / 32; ++it) {
            int slot = it * 256 + t;
            int row = slot >> 3, k8 = slot & 7;
            short8 v = *(const short8*)(Ws + (size_t)row * 128 + kloc + k8 * 8);
            *(short8*)((char*)sW + ((row * 128 + k8 * 16) ^ ((row & 7) << 4))) = v;
        }
        __syncthreads();

        #pragma unroll
        for (int kb = 0; kb < 2; ++kb) {
            short8 af[M_REP], bfr[N_REP];
            #pragma unroll
            for (int m = 0; m < M_REP; ++m) {
                int row = wm * WROWS + m * 16 + l15;
                af[m] = *(const short8*)((const char*)sA +
                        ((row * 128 + kb * 64 + lhi * 16) ^ ((row & 7) << 4)));
            }
            #pragma unroll
            for (int n = 0; n < N_REP; ++n) {
                int colr = wn0 + n * 16 + l15;
                bfr[n] = *(const short8*)((const char*)sW +
                         ((colr * 128 + kb * 64 + lhi * 16) ^ ((colr & 7) << 4)));
            }
            #pragma unroll
            for (int m = 0; m < M_REP; ++m)
                #pragma unroll
                for (int n = 0; n < N_REP; ++n)
                    acc[m][n] = __builtin_amdgcn_mfma_f32_16x16x32_bf16(af[m], bfr[n], acc[m][n], 0, 0, 0);
        }
    }

    float bv[N_REP];
    #pragma unroll
    for (int n = 0; n < N_REP; ++n) bv[n] = bias ? bias[wn0 + n * 16 + l15] : 0.f;

    #pragma unroll
    for (int m = 0; m < M_REP; ++m) {
        #pragma unroll
        for (int r = 0; r < 4; ++r) {
            int grow = r0 + wm * WROWS + m * 16 + lhi * 4 + r;
            if (grow < N) {
                #pragma unroll
                for (int n = 0; n < N_REP; ++n) {
                    int colr = wn0 + n * 16 + l15;
                    float v = acc[m][n][r] + bv[n];
                    if (HAS_ADD) v += bf2f(add[(size_t)grow * OD + colr]);
                    if (RELU) v = fmaxf(v, 0.f);
                    if (OUT_F32) ((float*)outp)[(size_t)grow * OD + colr] = v;
                    else ((ushort*)outp)[(size_t)grow * OD + colr] = f2bf(v);
                }
            }
        }
    }
}

extern "C" void kernel_launch(void* const* d_in, const int* in_sizes, int n_in,
                              void* d_out, int out_size, void* d_ws, size_t ws_size,
                              hipStream_t stream) {
    const float* x     = (const float*)d_in[0];
    const int*   eidx  = (const int*)d_in[1];
    const float* emb_W = (const float*)d_in[2];
    const float* emb_b = (const float*)d_in[3];
    const float* Wl0   = (const float*)d_in[4];
    const float* bl0   = (const float*)d_in[5];
    const float* Wr0   = (const float*)d_in[6];
    const float* Wl1   = (const float*)d_in[7];
    const float* bl1   = (const float*)d_in[8];
    const float* Wr1   = (const float*)d_in[9];
    const float* Wl2   = (const float*)d_in[10];
    const float* bl2   = (const float*)d_in[11];
    const float* Wr2   = (const float*)d_in[12];

    const int N = in_sizes[0] / NODE_D;
    const int E = in_sizes[1] / 2;
    const int* src = eidx;
    const int* dst = eidx + E;
    const int NC = (E + ECHUNK - 1) / ECHUNK;     // 196 chunks
    const int psz = (N + NPART - 1) / NPART;

    // ---- workspace layout ----
    char* w = (char*)d_ws;
    ushort* h_bf    = (ushort*)w; w += (size_t)N * 128 * sizeof(ushort);
    ushort* mean_bf = (ushort*)w; w += (size_t)N * 128 * sizeof(ushort);
    ushort* wbf     = (ushort*)w; w += (size_t)98304 * sizeof(ushort);
    uint2* ebuf     = (uint2*)w;  w += (size_t)E * sizeof(uint2);
    int* deg    = (int*)w; w += (size_t)N * sizeof(int);
    int* rowptr = (int*)w; w += (size_t)(N + 1) * sizeof(int);
    int* cursor = (int*)w; w += (size_t)N * sizeof(int);
    int* bsums  = (int*)w; w += (size_t)256 * sizeof(int);
    int* cm     = (int*)w; w += (size_t)NC * NPART * sizeof(int);
    int* om     = (int*)w; w += (size_t)NC * NPART * sizeof(int);
    int* pbase  = (int*)w; w += (size_t)(NPART + 1) * sizeof(int);
    int* col    = (int*)w; w += (size_t)E * sizeof(int);

    const ushort* embB = wbf;
    const ushort* Wl0B = wbf + 16384;
    const ushort* Wr0B = wbf + 32768;
    const ushort* Wl1B = wbf + 49152;
    const ushort* Wr1B = wbf + 65536;
    const ushort* Wl2B = wbf + 81920;
    const ushort* Wr2B = wbf + 90112;

    // layer-2 64-dim buffers alias mean_bf
    ushort* g2 = mean_bf;
    ushort* ga = mean_bf + (size_t)N * 64;

    const int TPB = 256;

    // ---- weight conversion ----
    hipLaunchKernelGGL(k_cvt_w, dim3(384), dim3(TPB), 0, stream,
                       emb_W, Wl0, Wr0, Wl1, Wr1, Wl2, Wr2, wbf);

    // ---- CSR build: hist+chunkcnt -> scans -> deterministic scatter -> local fill ----
    hipMemsetAsync(deg, 0, (size_t)N * sizeof(int), stream);
    hipLaunchKernelGGL(k_hist2, dim3(NC), dim3(TPB), 0, stream, dst, deg, cm, E, psz);
    const int NB = (N + SCAN_T * SCAN_I - 1) / (SCAN_T * SCAN_I);
    hipLaunchKernelGGL(k_scan_bsum, dim3(NB), dim3(SCAN_T), 0, stream, deg, bsums, N);
    hipLaunchKernelGGL(k_scan_bsum_excl, dim3(1), dim3(1), 0, stream, bsums, NB, rowptr + N);
    hipLaunchKernelGGL(k_scan_final, dim3(NB), dim3(SCAN_T), 0, stream, deg, bsums, rowptr, cursor, N);
    hipLaunchKernelGGL(k_cmscan, dim3(1), dim3(TPB), 0, stream, cm, om, pbase, NC);
    hipLaunchKernelGGL(k_scatter2, dim3(NC), dim3(TPB), 0, stream, src, dst, om, ebuf, E, psz);
    hipLaunchKernelGGL(k_fillq, dim3(512), dim3(TPB), 0, stream, ebuf, pbase, cursor, col);

    const int dgrid = (N + 127) / 128;
    const int agrid = (N + 3) / 4;

    // ---- embedding: h = x @ emb_W.T + emb_b (f32 A staged with in-reg convert) ----
    hipLaunchKernelGGL((k_mm<128, false, false, false, false, true>), dim3(dgrid), dim3(TPB), 0, stream,
                       (const void*)x, (const ushort*)nullptr, embB, (const ushort*)nullptr,
                       emb_b, (const ushort*)nullptr, h_bf, N);

    // ---- layer 0: h = relu(mean@Wl0.T + bl0 + h@Wr0.T) ----
    hipLaunchKernelGGL((k_aggb<128>), dim3(agrid), dim3(TPB), 0, stream, h_bf, rowptr, col, mean_bf, N);
    hipLaunchKernelGGL((k_mm<128, true, false, true, false, false>), dim3(dgrid), dim3(TPB), 0, stream,
                       (const void*)mean_bf, h_bf, Wl0B, Wr0B, bl0, (const ushort*)nullptr, h_bf, N);

    // ---- layer 1 ----
    hipLaunchKernelGGL((k_aggb<128>), dim3(agrid), dim3(TPB), 0, stream, h_bf, rowptr, col, mean_bf, N);
    hipLaunchKernelGGL((k_mm<128, true, false, true, false, false>), dim3(dgrid), dim3(TPB), 0, stream,
                       (const void*)mean_bf, h_bf, Wl1B, Wr1B, bl1, (const ushort*)nullptr, h_bf, N);

    // ---- layer 2: pre-transform (linearity), aggregate 64-dim, root + add ----
    hipLaunchKernelGGL((k_mm<64, false, false, false, false, false>), dim3(dgrid), dim3(TPB), 0, stream,
                       (const void*)h_bf, (const ushort*)nullptr, Wl2B, (const ushort*)nullptr,
                       (const float*)nullptr, (const ushort*)nullptr, g2, N);
    hipLaunchKernelGGL((k_aggb<64>), dim3(agrid), dim3(TPB), 0, stream, g2, rowptr, col, ga, N);
    hipLaunchKernelGGL((k_mm<64, false, true, false, true, false>), dim3(dgrid), dim3(TPB), 0, stream,
                       (const void*)h_bf, (const ushort*)nullptr, Wr2B, (const ushort*)nullptr,
                       bl2, ga, d_out, N);
}

// Round 7
// 451.781 us; speedup vs baseline: 1.0184x; 1.0184x over previous
//
#include <hip/hip_runtime.h>

typedef __attribute__((ext_vector_type(8))) short short8;
typedef __attribute__((ext_vector_type(4))) float f32x4;

#define NODE_D 128
#define SCAN_T 256
#define SCAN_I 8
#define NPART 8
#define ECHUNK 8192        // edges per counting/scatter chunk

__device__ __forceinline__ float bf2f(ushort u) {
    union { uint i; float f; } c; c.i = ((uint)u) << 16; return c.f;
}
__device__ __forceinline__ ushort f2bf(float f) {
    union { float f; uint i; } c; c.f = f;
    return (ushort)((c.i + 0x7FFF + ((c.i >> 16) & 1)) >> 16);
}

// ---------- fused: per-chunk histogram (blocks 0..NC) + weight cvt (blocks NC..NC+383) ----------
__global__ __launch_bounds__(256) void k_pre(const int* __restrict__ dst,
                                             int* __restrict__ deg,
                                             int* __restrict__ cm,
                                             int E, int psz, int NC,
                                             const float* __restrict__ s0, const float* __restrict__ s1,
                                             const float* __restrict__ s2, const float* __restrict__ s3,
                                             const float* __restrict__ s4, const float* __restrict__ s5,
                                             const float* __restrict__ s6, ushort* __restrict__ wdst) {
    if ((int)blockIdx.x >= NC) {
        int i = ((int)blockIdx.x - NC) * 256 + threadIdx.x;
        if (i >= 98304) return;
        const float* s; int off;
        if (i < 16384)      { s = s0; off = i; }
        else if (i < 32768) { s = s1; off = i - 16384; }
        else if (i < 49152) { s = s2; off = i - 32768; }
        else if (i < 65536) { s = s3; off = i - 49152; }
        else if (i < 81920) { s = s4; off = i - 65536; }
        else if (i < 90112) { s = s5; off = i - 81920; }
        else                { s = s6; off = i - 90112; }
        wdst[i] = f2bf(s[off]);
        return;
    }
    __shared__ int lh[NPART];
    if (threadIdx.x < NPART) lh[threadIdx.x] = 0;
    __syncthreads();
    int c = blockIdx.x;
    int lo = c * ECHUNK, hi = min(lo + ECHUNK, E);
    for (int i = lo + (int)threadIdx.x; i < hi; i += 256) {
        int d = dst[i];
        atomicAdd(&deg[d], 1);
        atomicAdd(&lh[d / psz], 1);
    }
    __syncthreads();
    if (threadIdx.x < NPART) cm[c * NPART + threadIdx.x] = lh[threadIdx.x];
}

// ---------- scan pass A ----------
__global__ __launch_bounds__(SCAN_T) void k_scan_bsum(const int* __restrict__ deg,
                                                      int* __restrict__ bsums, int n) {
    __shared__ int red[SCAN_T];
    int base = blockIdx.x * SCAN_T * SCAN_I + threadIdx.x * SCAN_I;
    int s = 0;
    #pragma unroll
    for (int i = 0; i < SCAN_I; ++i) {
        int idx = base + i;
        if (idx < n) s += deg[idx];
    }
    red[threadIdx.x] = s;
    __syncthreads();
    for (int st = SCAN_T / 2; st > 0; st >>= 1) {
        if (threadIdx.x < st) red[threadIdx.x] += red[threadIdx.x + st];
        __syncthreads();
    }
    if (threadIdx.x == 0) bsums[blockIdx.x] = red[0];
}

// ---------- fused: block 0 = exclusive scan of bsums; block 1 = chunk-matrix scan ----------
__global__ __launch_bounds__(256) void k_scan_mid(int* __restrict__ bsums, int nb,
                                                  int* __restrict__ rowptr_last,
                                                  const int* __restrict__ cm,
                                                  int* __restrict__ om,
                                                  int* __restrict__ pbase, int NC) {
    if (blockIdx.x == 0) {
        if (threadIdx.x == 0) {
            int run = 0;
            for (int i = 0; i < nb; ++i) {
                int v = bsums[i];
                bsums[i] = run;
                run += v;
            }
            rowptr_last[0] = run;
        }
        return;
    }
    // chunk x partition matrix scan (partition-major order)
    __shared__ int ts[256];
    int total = NC * NPART;
    int base = threadIdx.x * 8;
    int v[8];
    int s = 0;
    #pragma unroll
    for (int i = 0; i < 8; ++i) {
        int e = base + i;
        if (e < total) { int p = e / NC; int c = e - p * NC; v[i] = cm[c * NPART + p]; }
        else v[i] = 0;
        s += v[i];
    }
    ts[threadIdx.x] = s;
    __syncthreads();
    for (int st = 1; st < 256; st <<= 1) {
        int add = (threadIdx.x >= st) ? ts[threadIdx.x - st] : 0;
        __syncthreads();
        ts[threadIdx.x] += add;
        __syncthreads();
    }
    int excl = (threadIdx.x == 0 ? 0 : ts[threadIdx.x - 1]);
    #pragma unroll
    for (int i = 0; i < 8; ++i) {
        int e = base + i;
        if (e < total) {
            int p = e / NC; int c = e - p * NC;
            om[c * NPART + p] = excl;
            if (c == 0) pbase[p] = excl;
        }
        excl += v[i];
    }
    if (threadIdx.x == 255) pbase[NPART] = ts[255];
}

// ---------- scan pass C ----------
__global__ __launch_bounds__(SCAN_T) void k_scan_final(const int* __restrict__ deg,
                                                       const int* __restrict__ bsums,
                                                       int* __restrict__ rowptr,
                                                       int* __restrict__ cursor, int n) {
    __shared__ int ts[SCAN_T];
    int base = blockIdx.x * SCAN_T * SCAN_I + threadIdx.x * SCAN_I;
    int v[SCAN_I];
    int s = 0;
    #pragma unroll
    for (int i = 0; i < SCAN_I; ++i) {
        int idx = base + i;
        v[i] = (idx < n) ? deg[idx] : 0;
        s += v[i];
    }
    ts[threadIdx.x] = s;
    __syncthreads();
    for (int st = 1; st < SCAN_T; st <<= 1) {
        int add = (threadIdx.x >= st) ? ts[threadIdx.x - st] : 0;
        __syncthreads();
        ts[threadIdx.x] += add;
        __syncthreads();
    }
    int excl = (threadIdx.x == 0 ? 0 : ts[threadIdx.x - 1]) + bsums[blockIdx.x];
    #pragma unroll
    for (int i = 0; i < SCAN_I; ++i) {
        int idx = base + i;
        if (idx < n) { rowptr[idx] = excl; cursor[idx] = excl; }
        excl += v[i];
    }
}

// ---------- deterministic scatter: chunk edges -> partition-major ebuf ----------
__global__ __launch_bounds__(256) void k_scatter2(const int* __restrict__ src,
                                                  const int* __restrict__ dst,
                                                  const int* __restrict__ om,
                                                  uint2* __restrict__ ebuf,
                                                  int E, int psz) {
    __shared__ int cur[NPART];
    int c = blockIdx.x;
    if (threadIdx.x < NPART) cur[threadIdx.x] = om[c * NPART + threadIdx.x];
    __syncthreads();
    int lo = c * ECHUNK, hi = min(lo + ECHUNK, E);
    for (int i = lo + (int)threadIdx.x; i < hi; i += 256) {
        int d = dst[i];
        int pos = atomicAdd(&cur[d / psz], 1);
        uint2 e; e.x = (uint)src[i]; e.y = (uint)d;
        ebuf[pos] = e;
    }
}

// ---------- final CSR fill from partition-major ebuf (XCD-aligned partitions) ----------
__global__ __launch_bounds__(256) void k_fillq(const uint2* __restrict__ ebuf,
                                               const int* __restrict__ pbase,
                                               int* __restrict__ cursor,
                                               int* __restrict__ col) {
    int p = blockIdx.x & 7;
    int sb = blockIdx.x >> 3;
    int lo = pbase[p], hi = pbase[p + 1];
    int stride = (gridDim.x >> 3) * 256;
    for (int j = lo + sb * 256 + (int)threadIdx.x; j < hi; j += stride) {
        uint2 e = ebuf[j];
        int pos = atomicAdd(&cursor[e.y], 1);
        col[pos] = (int)e.x;
    }
}

// ---------- mean aggregation v2: one wave per node, half-wave per row ----------
// D=128: 32 lanes x uint2 = full 256B row; 16 neighbor rows in flight per wave.
// D=64:  32 lanes x uint  = full 128B row.
// Halves combined at the end via __shfl_xor(.,32); lanes 0-31 write packed row.
template<int D>
__global__ __launch_bounds__(256) void k_aggb(const ushort* __restrict__ h,
                                              const int* __restrict__ rowptr,
                                              const int* __restrict__ col,
                                              ushort* __restrict__ mean, int N) {
    int node = blockIdx.x * 4 + (threadIdx.x >> 6);
    if (node >= N) return;
    int lane = threadIdx.x & 63;
    int half = lane >> 5;
    int l32  = lane & 31;
    int beg = rowptr[node];
    int end = rowptr[node + 1];
    float inv = 1.f / fmaxf((float)(end - beg), 1.f);

    if constexpr (D == 128) {
        const ushort* base = h + l32 * 4;       // lane covers cols l32*4 .. l32*4+3
        float a0 = 0.f, a1 = 0.f, a2 = 0.f, a3 = 0.f;
        int jb = beg;
        for (; jb + 15 < end; jb += 16) {
            uint2 v[8];
            #pragma unroll
            for (int q = 0; q < 8; ++q) {
                int s = col[jb + half * 8 + q];
                v[q] = *(const uint2*)(base + (size_t)s * 128);
            }
            #pragma unroll
            for (int q = 0; q < 8; ++q) {
                a0 += bf2f((ushort)v[q].x); a1 += bf2f((ushort)(v[q].x >> 16));
                a2 += bf2f((ushort)v[q].y); a3 += bf2f((ushort)(v[q].y >> 16));
            }
        }
        for (; jb + 1 < end; jb += 2) {
            int s = col[jb + half];
            uint2 v = *(const uint2*)(base + (size_t)s * 128);
            a0 += bf2f((ushort)v.x); a1 += bf2f((ushort)(v.x >> 16));
            a2 += bf2f((ushort)v.y); a3 += bf2f((ushort)(v.y >> 16));
        }
        if (jb < end && half == 0) {
            int s = col[jb];
            uint2 v = *(const uint2*)(base + (size_t)s * 128);
            a0 += bf2f((ushort)v.x); a1 += bf2f((ushort)(v.x >> 16));
            a2 += bf2f((ushort)v.y); a3 += bf2f((ushort)(v.y >> 16));
        }
        a0 += __shfl_xor(a0, 32); a1 += __shfl_xor(a1, 32);
        a2 += __shfl_xor(a2, 32); a3 += __shfl_xor(a3, 32);
        if (half == 0) {
            uint2 o;
            o.x = (uint)f2bf(a0 * inv) | ((uint)f2bf(a1 * inv) << 16);
            o.y = (uint)f2bf(a2 * inv) | ((uint)f2bf(a3 * inv) << 16);
            *(uint2*)(mean + (size_t)node * 128 + l32 * 4) = o;
        }
    } else {
        const ushort* base = h + l32 * 2;       // lane covers cols l32*2, l32*2+1
        float a0 = 0.f, a1 = 0.f;
        int jb = beg;
        for (; jb + 15 < end; jb += 16) {
            uint v[8];
            #pragma unroll
            for (int q = 0; q < 8; ++q) {
                int s = col[jb + half * 8 + q];
                v[q] = *(const uint*)(base + (size_t)s * D);
            }
            #pragma unroll
            for (int q = 0; q < 8; ++q) {
                a0 += bf2f((ushort)v[q]); a1 += bf2f((ushort)(v[q] >> 16));
            }
        }
        for (; jb + 1 < end; jb += 2) {
            int s = col[jb + half];
            uint v = *(const uint*)(base + (size_t)s * D);
            a0 += bf2f((ushort)v); a1 += bf2f((ushort)(v >> 16));
        }
        if (jb < end && half == 0) {
            int s = col[jb];
            uint v = *(const uint*)(base + (size_t)s * D);
            a0 += bf2f((ushort)v); a1 += bf2f((ushort)(v >> 16));
        }
        a0 += __shfl_xor(a0, 32); a1 += __shfl_xor(a1, 32);
        if (half == 0) {
            uint o = (uint)f2bf(a0 * inv) | ((uint)f2bf(a1 * inv) << 16);
            *(uint*)(mean + (size_t)node * D + l32 * 2) = o;
        }
    }
}

// ---------- MFMA dense: out = A@W0^T (+ A1@W1^T) [+bias] [+add] [+relu] ----------
// A0: [N][128] bf16 (or f32 if A0F32) row-major. W: [OD][128] bf16 row-major.
// Tile: 128 rows x OD cols, 4 waves. LDS [dim][64] bf16, XOR swizzle byte^=((row&7)<<4).
template<int OD, bool DUAL, bool HAS_ADD, bool RELU, bool OUT_F32, bool A0F32>
__global__ __launch_bounds__(256) void k_mm(const void* __restrict__ A0,
                                            const ushort* __restrict__ A1,
                                            const ushort* __restrict__ W0,
                                            const ushort* __restrict__ W1,
                                            const float* __restrict__ bias,
                                            const ushort* __restrict__ add,
                                            void* __restrict__ outp, int N) {
    constexpr int NK    = DUAL ? 4 : 2;
    constexpr int M_REP = (OD == 128) ? 4 : 2;
    constexpr int N_REP = 4;
    constexpr int WROWS = M_REP * 16;

    __shared__ __align__(16) ushort sA[128 * 64];
    __shared__ __align__(16) ushort sW[OD * 64];

    const int t    = threadIdx.x;
    const int wid  = t >> 6;
    const int lane = t & 63;
    const int l15  = lane & 15;
    const int lhi  = lane >> 4;
    const int r0   = blockIdx.x * 128;

    int wm, wn0;
    if (OD == 128) { wm = wid >> 1; wn0 = (wid & 1) * 64; }
    else           { wm = wid;      wn0 = 0; }

    f32x4 zero = {0.f, 0.f, 0.f, 0.f};
    f32x4 acc[M_REP][N_REP];
    #pragma unroll
    for (int m = 0; m < M_REP; ++m)
        #pragma unroll
        for (int n = 0; n < N_REP; ++n) acc[m][n] = zero;

    const ushort* A0b = (const ushort*)A0;
    const float*  A0f = (const float*)A0;

    for (int kc = 0; kc < NK; ++kc) {
        const ushort* Ws = (DUAL && kc >= 2) ? W1 : W0;
        const ushort* As = (DUAL && kc >= 2) ? A1 : A0b;
        const int kloc = (kc & 1) * 64;

        __syncthreads();
        // stage A tile: 128 rows x 64 k
        #pragma unroll
        for (int it = 0; it < 4; ++it) {
            int slot = it * 256 + t;
            int row = slot >> 3, k8 = slot & 7;
            int gr = r0 + row; if (gr >= N) gr = N - 1;
            short8 v;
            if constexpr (A0F32) {
                float4 p = *(const float4*)(A0f + (size_t)gr * 128 + kloc + k8 * 8);
                float4 q = *(const float4*)(A0f + (size_t)gr * 128 + kloc + k8 * 8 + 4);
                v[0] = (short)f2bf(p.x); v[1] = (short)f2bf(p.y);
                v[2] = (short)f2bf(p.z); v[3] = (short)f2bf(p.w);
                v[4] = (short)f2bf(q.x); v[5] = (short)f2bf(q.y);
                v[6] = (short)f2bf(q.z); v[7] = (short)f2bf(q.w);
            } else {
                v = *(const short8*)(As + (size_t)gr * 128 + kloc + k8 * 8);
            }
            *(short8*)((char*)sA + ((row * 128 + k8 * 16) ^ ((row & 7) << 4))) = v;
        }
        // stage W tile: OD rows x 64 k
        #pragma unroll
        for (int it = 0; it < OD / 32; ++it) {
            int slot = it * 256 + t;
            int row = slot >> 3, k8 = slot & 7;
            short8 v = *(const short8*)(Ws + (size_t)row * 128 + kloc + k8 * 8);
            *(short8*)((char*)sW + ((row * 128 + k8 * 16) ^ ((row & 7) << 4))) = v;
        }
        __syncthreads();

        #pragma unroll
        for (int kb = 0; kb < 2; ++kb) {
            short8 af[M_REP], bfr[N_REP];
            #pragma unroll
            for (int m = 0; m < M_REP; ++m) {
                int row = wm * WROWS + m * 16 + l15;
                af[m] = *(const short8*)((const char*)sA +
                        ((row * 128 + kb * 64 + lhi * 16) ^ ((row & 7) << 4)));
            }
            #pragma unroll
            for (int n = 0; n < N_REP; ++n) {
                int colr = wn0 + n * 16 + l15;
                bfr[n] = *(const short8*)((const char*)sW +
                         ((colr * 128 + kb * 64 + lhi * 16) ^ ((colr & 7) << 4)));
            }
            #pragma unroll
            for (int m = 0; m < M_REP; ++m)
                #pragma unroll
                for (int n = 0; n < N_REP; ++n)
                    acc[m][n] = __builtin_amdgcn_mfma_f32_16x16x32_bf16(af[m], bfr[n], acc[m][n], 0, 0, 0);
        }
    }

    float bv[N_REP];
    #pragma unroll
    for (int n = 0; n < N_REP; ++n) bv[n] = bias ? bias[wn0 + n * 16 + l15] : 0.f;

    #pragma unroll
    for (int m = 0; m < M_REP; ++m) {
        #pragma unroll
        for (int r = 0; r < 4; ++r) {
            int grow = r0 + wm * WROWS + m * 16 + lhi * 4 + r;
            if (grow < N) {
                #pragma unroll
                for (int n = 0; n < N_REP; ++n) {
                    int colr = wn0 + n * 16 + l15;
                    float v = acc[m][n][r] + bv[n];
                    if (HAS_ADD) v += bf2f(add[(size_t)grow * OD + colr]);
                    if (RELU) v = fmaxf(v, 0.f);
                    if (OUT_F32) ((float*)outp)[(size_t)grow * OD + colr] = v;
                    else ((ushort*)outp)[(size_t)grow * OD + colr] = f2bf(v);
                }
            }
        }
    }
}

extern "C" void kernel_launch(void* const* d_in, const int* in_sizes, int n_in,
                              void* d_out, int out_size, void* d_ws, size_t ws_size,
                              hipStream_t stream) {
    const float* x     = (const float*)d_in[0];
    const int*   eidx  = (const int*)d_in[1];
    const float* emb_W = (const float*)d_in[2];
    const float* emb_b = (const float*)d_in[3];
    const float* Wl0   = (const float*)d_in[4];
    const float* bl0   = (const float*)d_in[5];
    const float* Wr0   = (const float*)d_in[6];
    const float* Wl1   = (const float*)d_in[7];
    const float* bl1   = (const float*)d_in[8];
    const float* Wr1   = (const float*)d_in[9];
    const float* Wl2   = (const float*)d_in[10];
    const float* bl2   = (const float*)d_in[11];
    const float* Wr2   = (const float*)d_in[12];

    const int N = in_sizes[0] / NODE_D;
    const int E = in_sizes[1] / 2;
    const int* src = eidx;
    const int* dst = eidx + E;
    const int NC = (E + ECHUNK - 1) / ECHUNK;
    const int psz = (N + NPART - 1) / NPART;

    // ---- workspace layout ----
    char* w = (char*)d_ws;
    ushort* h_bf    = (ushort*)w; w += (size_t)N * 128 * sizeof(ushort);
    ushort* mean_bf = (ushort*)w; w += (size_t)N * 128 * sizeof(ushort);
    ushort* wbf     = (ushort*)w; w += (size_t)98304 * sizeof(ushort);
    uint2* ebuf     = (uint2*)w;  w += (size_t)E * sizeof(uint2);
    int* deg    = (int*)w; w += (size_t)N * sizeof(int);
    int* rowptr = (int*)w; w += (size_t)(N + 1) * sizeof(int);
    int* cursor = (int*)w; w += (size_t)N * sizeof(int);
    int* bsums  = (int*)w; w += (size_t)256 * sizeof(int);
    int* cm     = (int*)w; w += (size_t)NC * NPART * sizeof(int);
    int* om     = (int*)w; w += (size_t)NC * NPART * sizeof(int);
    int* pbase  = (int*)w; w += (size_t)(NPART + 1) * sizeof(int);
    int* col    = (int*)w; w += (size_t)E * sizeof(int);

    const ushort* embB = wbf;
    const ushort* Wl0B = wbf + 16384;
    const ushort* Wr0B = wbf + 32768;
    const ushort* Wl1B = wbf + 49152;
    const ushort* Wr1B = wbf + 65536;
    const ushort* Wl2B = wbf + 81920;
    const ushort* Wr2B = wbf + 90112;

    // layer-2 64-dim buffers alias mean_bf
    ushort* g2 = mean_bf;
    ushort* ga = mean_bf + (size_t)N * 64;

    const int TPB = 256;

    // ---- CSR build + weight cvt (fused) ----
    hipMemsetAsync(deg, 0, (size_t)N * sizeof(int), stream);
    hipLaunchKernelGGL(k_pre, dim3(NC + 384), dim3(TPB), 0, stream,
                       dst, deg, cm, E, psz, NC,
                       emb_W, Wl0, Wr0, Wl1, Wr1, Wl2, Wr2, wbf);
    const int NB = (N + SCAN_T * SCAN_I - 1) / (SCAN_T * SCAN_I);
    hipLaunchKernelGGL(k_scan_bsum, dim3(NB), dim3(SCAN_T), 0, stream, deg, bsums, N);
    hipLaunchKernelGGL(k_scan_mid, dim3(2), dim3(TPB), 0, stream,
                       bsums, NB, rowptr + N, cm, om, pbase, NC);
    hipLaunchKernelGGL(k_scan_final, dim3(NB), dim3(SCAN_T), 0, stream, deg, bsums, rowptr, cursor, N);
    hipLaunchKernelGGL(k_scatter2, dim3(NC), dim3(TPB), 0, stream, src, dst, om, ebuf, E, psz);
    hipLaunchKernelGGL(k_fillq, dim3(512), dim3(TPB), 0, stream, ebuf, pbase, cursor, col);

    const int dgrid = (N + 127) / 128;
    const int agrid = (N + 3) / 4;

    // ---- embedding: h = x @ emb_W.T + emb_b (f32 A staged with in-reg convert) ----
    hipLaunchKernelGGL((k_mm<128, false, false, false, false, true>), dim3(dgrid), dim3(TPB), 0, stream,
                       (const void*)x, (const ushort*)nullptr, embB, (const ushort*)nullptr,
                       emb_b, (const ushort*)nullptr, h_bf, N);

    // ---- layer 0: h = relu(mean@Wl0.T + bl0 + h@Wr0.T) ----
    hipLaunchKernelGGL((k_aggb<128>), dim3(agrid), dim3(TPB), 0, stream, h_bf, rowptr, col, mean_bf, N);
    hipLaunchKernelGGL((k_mm<128, true, false, true, false, false>), dim3(dgrid), dim3(TPB), 0, stream,
                       (const void*)mean_bf, h_bf, Wl0B, Wr0B, bl0, (const ushort*)nullptr, h_bf, N);

    // ---- layer 1 ----
    hipLaunchKernelGGL((k_aggb<128>), dim3(agrid), dim3(TPB), 0, stream, h_bf, rowptr, col, mean_bf, N);
    hipLaunchKernelGGL((k_mm<128, true, false, true, false, false>), dim3(dgrid), dim3(TPB), 0, stream,
                       (const void*)mean_bf, h_bf, Wl1B, Wr1B, bl1, (const ushort*)nullptr, h_bf, N);

    // ---- layer 2: pre-transform (linearity), aggregate 64-dim, root + add ----
    hipLaunchKernelGGL((k_mm<64, false, false, false, false, false>), dim3(dgrid), dim3(TPB), 0, stream,
                       (const void*)h_bf, (const ushort*)nullptr, Wl2B, (const ushort*)nullptr,
                       (const float*)nullptr, (const ushort*)nullptr, g2, N);
    hipLaunchKernelGGL((k_aggb<64>), dim3(agrid), dim3(TPB), 0, stream, g2, rowptr, col, ga, N);
    hipLaunchKernelGGL((k_mm<64, false, true, false, true, false>), dim3(dgrid), dim3(TPB), 0, stream,
                       (const void*)h_bf, (const ushort*)nullptr, Wr2B, (const ushort*)nullptr,
                       bl2, ga, d_out, N);
}

// Round 8
// 426.154 us; speedup vs baseline: 1.0796x; 1.0601x over previous
//
#include <hip/hip_runtime.h>

typedef __attribute__((ext_vector_type(8))) short short8;
typedef __attribute__((ext_vector_type(4))) float f32x4;
typedef __attribute__((ext_vector_type(2))) float f32x2;

#define NODE_D 128
#define SCAN_T 256
#define SCAN_I 8
#define NPART 8
#define ECHUNK 8192        // edges per counting/scatter chunk

__device__ __forceinline__ float bf2f(ushort u) {
    union { uint i; float f; } c; c.i = ((uint)u) << 16; return c.f;
}
__device__ __forceinline__ ushort f2bf(float f) {
    union { float f; uint i; } c; c.f = f;
    return (ushort)((c.i + 0x7FFF + ((c.i >> 16) & 1)) >> 16);
}
__device__ __forceinline__ uchar f2e4m3(float f) {
    uint w = (uint)__builtin_amdgcn_cvt_pk_fp8_f32(f, f, 0, false);
    return (uchar)(w & 0xff);
}

// ---------- fused: per-chunk histogram (blocks 0..NC) + weight cvt (blocks NC..NC+383) ----------
__global__ __launch_bounds__(256) void k_pre(const int* __restrict__ dst,
                                             int* __restrict__ deg,
                                             int* __restrict__ cm,
                                             int E, int psz, int NC,
                                             const float* __restrict__ s0, const float* __restrict__ s1,
                                             const float* __restrict__ s2, const float* __restrict__ s3,
                                             const float* __restrict__ s4, const float* __restrict__ s5,
                                             const float* __restrict__ s6, ushort* __restrict__ wdst) {
    if ((int)blockIdx.x >= NC) {
        int i = ((int)blockIdx.x - NC) * 256 + threadIdx.x;
        if (i >= 98304) return;
        const float* s; int off;
        if (i < 16384)      { s = s0; off = i; }
        else if (i < 32768) { s = s1; off = i - 16384; }
        else if (i < 49152) { s = s2; off = i - 32768; }
        else if (i < 65536) { s = s3; off = i - 49152; }
        else if (i < 81920) { s = s4; off = i - 65536; }
        else if (i < 90112) { s = s5; off = i - 81920; }
        else                { s = s6; off = i - 90112; }
        wdst[i] = f2bf(s[off]);
        return;
    }
    __shared__ int lh[NPART];
    if (threadIdx.x < NPART) lh[threadIdx.x] = 0;
    __syncthreads();
    int c = blockIdx.x;
    int lo = c * ECHUNK, hi = min(lo + ECHUNK, E);
    for (int i = lo + (int)threadIdx.x; i < hi; i += 256) {
        int d = dst[i];
        atomicAdd(&deg[d], 1);
        atomicAdd(&lh[d / psz], 1);
    }
    __syncthreads();
    if (threadIdx.x < NPART) cm[c * NPART + threadIdx.x] = lh[threadIdx.x];
}

// ---------- scan pass A ----------
__global__ __launch_bounds__(SCAN_T) void k_scan_bsum(const int* __restrict__ deg,
                                                      int* __restrict__ bsums, int n) {
    __shared__ int red[SCAN_T];
    int base = blockIdx.x * SCAN_T * SCAN_I + threadIdx.x * SCAN_I;
    int s = 0;
    #pragma unroll
    for (int i = 0; i < SCAN_I; ++i) {
        int idx = base + i;
        if (idx < n) s += deg[idx];
    }
    red[threadIdx.x] = s;
    __syncthreads();
    for (int st = SCAN_T / 2; st > 0; st >>= 1) {
        if (threadIdx.x < st) red[threadIdx.x] += red[threadIdx.x + st];
        __syncthreads();
    }
    if (threadIdx.x == 0) bsums[blockIdx.x] = red[0];
}

// ---------- fused: block 0 = parallel excl scan of bsums (nb<=256); block 1 = chunk-matrix scan ----------
__global__ __launch_bounds__(256) void k_scan_mid(int* __restrict__ bsums, int nb,
                                                  int* __restrict__ rowptr_last,
                                                  const int* __restrict__ cm,
                                                  int* __restrict__ om,
                                                  int* __restrict__ pbase, int NC) {
    if (blockIdx.x == 0) {
        __shared__ int sb[256];
        int tid = threadIdx.x;
        sb[tid] = (tid < nb) ? bsums[tid] : 0;
        __syncthreads();
        for (int st = 1; st < 256; st <<= 1) {
            int add = (tid >= st) ? sb[tid - st] : 0;
            __syncthreads();
            sb[tid] += add;
            __syncthreads();
        }
        if (tid < nb) bsums[tid] = (tid == 0) ? 0 : sb[tid - 1];
        if (tid == 0) rowptr_last[0] = sb[nb - 1];
        return;
    }
    // chunk x partition matrix scan (partition-major order)
    __shared__ int ts[256];
    int total = NC * NPART;
    int base = threadIdx.x * 8;
    int v[8];
    int s = 0;
    #pragma unroll
    for (int i = 0; i < 8; ++i) {
        int e = base + i;
        if (e < total) { int p = e / NC; int c = e - p * NC; v[i] = cm[c * NPART + p]; }
        else v[i] = 0;
        s += v[i];
    }
    ts[threadIdx.x] = s;
    __syncthreads();
    for (int st = 1; st < 256; st <<= 1) {
        int add = (threadIdx.x >= st) ? ts[threadIdx.x - st] : 0;
        __syncthreads();
        ts[threadIdx.x] += add;
        __syncthreads();
    }
    int excl = (threadIdx.x == 0 ? 0 : ts[threadIdx.x - 1]);
    #pragma unroll
    for (int i = 0; i < 8; ++i) {
        int e = base + i;
        if (e < total) {
            int p = e / NC; int c = e - p * NC;
            om[c * NPART + p] = excl;
            if (c == 0) pbase[p] = excl;
        }
        excl += v[i];
    }
    if (threadIdx.x == 255) pbase[NPART] = ts[255];
}

// ---------- scan pass C ----------
__global__ __launch_bounds__(SCAN_T) void k_scan_final(const int* __restrict__ deg,
                                                       const int* __restrict__ bsums,
                                                       int* __restrict__ rowptr,
                                                       int* __restrict__ cursor, int n) {
    __shared__ int ts[SCAN_T];
    int base = blockIdx.x * SCAN_T * SCAN_I + threadIdx.x * SCAN_I;
    int v[SCAN_I];
    int s = 0;
    #pragma unroll
    for (int i = 0; i < SCAN_I; ++i) {
        int idx = base + i;
        v[i] = (idx < n) ? deg[idx] : 0;
        s += v[i];
    }
    ts[threadIdx.x] = s;
    __syncthreads();
    for (int st = 1; st < SCAN_T; st <<= 1) {
        int add = (threadIdx.x >= st) ? ts[threadIdx.x - st] : 0;
        __syncthreads();
        ts[threadIdx.x] += add;
        __syncthreads();
    }
    int excl = (threadIdx.x == 0 ? 0 : ts[threadIdx.x - 1]) + bsums[blockIdx.x];
    #pragma unroll
    for (int i = 0; i < SCAN_I; ++i) {
        int idx = base + i;
        if (idx < n) { rowptr[idx] = excl; cursor[idx] = excl; }
        excl += v[i];
    }
}

// ---------- deterministic scatter: chunk edges -> partition-major ebuf ----------
__global__ __launch_bounds__(256) void k_scatter2(const int* __restrict__ src,
                                                  const int* __restrict__ dst,
                                                  const int* __restrict__ om,
                                                  uint2* __restrict__ ebuf,
                                                  int E, int psz) {
    __shared__ int cur[NPART];
    int c = blockIdx.x;
    if (threadIdx.x < NPART) cur[threadIdx.x] = om[c * NPART + threadIdx.x];
    __syncthreads();
    int lo = c * ECHUNK, hi = min(lo + ECHUNK, E);
    for (int i = lo + (int)threadIdx.x; i < hi; i += 256) {
        int d = dst[i];
        int pos = atomicAdd(&cur[d / psz], 1);
        uint2 e; e.x = (uint)src[i]; e.y = (uint)d;
        ebuf[pos] = e;
    }
}

// ---------- final CSR fill from partition-major ebuf (XCD-aligned partitions) ----------
__global__ __launch_bounds__(256) void k_fillq(const uint2* __restrict__ ebuf,
                                               const int* __restrict__ pbase,
                                               int* __restrict__ cursor,
                                               int* __restrict__ col) {
    int p = blockIdx.x & 7;
    int sb = blockIdx.x >> 3;
    int lo = pbase[p], hi = pbase[p + 1];
    int stride = (gridDim.x >> 3) * 256;
    for (int j = lo + sb * 256 + (int)threadIdx.x; j < hi; j += stride) {
        uint2 e = ebuf[j];
        int pos = atomicAdd(&cursor[e.y], 1);
        col[pos] = (int)e.x;
    }
}

// ---------- mean aggregation over fp8(e4m3) activations -> bf16 mean ----------
// D=128: row=128B, 32 lanes x uint (4 fp8 cols/lane); half-wave per neighbor parity.
// D=64:  row=64B, 16 lanes x uint; 4 neighbor groups per wave.
template<int D>
__global__ __launch_bounds__(256) void k_aggf(const uchar* __restrict__ hq,
                                              const int* __restrict__ rowptr,
                                              const int* __restrict__ col,
                                              ushort* __restrict__ mean, int N) {
    int node = blockIdx.x * 4 + (threadIdx.x >> 6);
    if (node >= N) return;
    int lane = threadIdx.x & 63;
    int beg = rowptr[node];
    int end = rowptr[node + 1];
    float inv = 1.f / fmaxf((float)(end - beg), 1.f);

    if constexpr (D == 128) {
        int half = lane >> 5;
        int l32  = lane & 31;
        const uchar* base = hq + l32 * 4;        // cols l32*4 .. l32*4+3
        float a0 = 0.f, a1 = 0.f, a2 = 0.f, a3 = 0.f;
        int jb = beg;
        for (; jb + 15 < end; jb += 16) {
            uint v[8];
            #pragma unroll
            for (int q = 0; q < 8; ++q) {
                int s = col[jb + half * 8 + q];
                v[q] = *(const uint*)(base + (size_t)s * 128);
            }
            #pragma unroll
            for (int q = 0; q < 8; ++q) {
                f32x2 lo = __builtin_amdgcn_cvt_pk_f32_fp8(v[q], false);
                f32x2 hi = __builtin_amdgcn_cvt_pk_f32_fp8(v[q], true);
                a0 += lo[0]; a1 += lo[1]; a2 += hi[0]; a3 += hi[1];
            }
        }
        for (; jb + 1 < end; jb += 2) {
            uint v = *(const uint*)(base + (size_t)col[jb + half] * 128);
            f32x2 lo = __builtin_amdgcn_cvt_pk_f32_fp8(v, false);
            f32x2 hi = __builtin_amdgcn_cvt_pk_f32_fp8(v, true);
            a0 += lo[0]; a1 += lo[1]; a2 += hi[0]; a3 += hi[1];
        }
        if (jb < end && half == 0) {
            uint v = *(const uint*)(base + (size_t)col[jb] * 128);
            f32x2 lo = __builtin_amdgcn_cvt_pk_f32_fp8(v, false);
            f32x2 hi = __builtin_amdgcn_cvt_pk_f32_fp8(v, true);
            a0 += lo[0]; a1 += lo[1]; a2 += hi[0]; a3 += hi[1];
        }
        a0 += __shfl_xor(a0, 32); a1 += __shfl_xor(a1, 32);
        a2 += __shfl_xor(a2, 32); a3 += __shfl_xor(a3, 32);
        if (half == 0) {
            uint2 o;
            o.x = (uint)f2bf(a0 * inv) | ((uint)f2bf(a1 * inv) << 16);
            o.y = (uint)f2bf(a2 * inv) | ((uint)f2bf(a3 * inv) << 16);
            *(uint2*)(mean + (size_t)node * 128 + l32 * 4) = o;
        }
    } else {
        int g   = lane >> 4;                     // neighbor group 0..3
        int c16 = lane & 15;
        const uchar* base = hq + c16 * 4;        // cols c16*4 .. c16*4+3
        float a0 = 0.f, a1 = 0.f, a2 = 0.f, a3 = 0.f;
        int jb = beg;
        for (; jb + 31 < end; jb += 32) {
            uint v[8];
            #pragma unroll
            for (int q = 0; q < 8; ++q) {
                int s = col[jb + g * 8 + q];
                v[q] = *(const uint*)(base + (size_t)s * 64);
            }
            #pragma unroll
            for (int q = 0; q < 8; ++q) {
                f32x2 lo = __builtin_amdgcn_cvt_pk_f32_fp8(v[q], false);
                f32x2 hi = __builtin_amdgcn_cvt_pk_f32_fp8(v[q], true);
                a0 += lo[0]; a1 += lo[1]; a2 += hi[0]; a3 += hi[1];
            }
        }
        for (; jb + 3 < end; jb += 4) {
            uint v = *(const uint*)(base + (size_t)col[jb + g] * 64);
            f32x2 lo = __builtin_amdgcn_cvt_pk_f32_fp8(v, false);
            f32x2 hi = __builtin_amdgcn_cvt_pk_f32_fp8(v, true);
            a0 += lo[0]; a1 += lo[1]; a2 += hi[0]; a3 += hi[1];
        }
        int rem = end - jb;
        if (g < rem) {
            uint v = *(const uint*)(base + (size_t)col[jb + g] * 64);
            f32x2 lo = __builtin_amdgcn_cvt_pk_f32_fp8(v, false);
            f32x2 hi = __builtin_amdgcn_cvt_pk_f32_fp8(v, true);
            a0 += lo[0]; a1 += lo[1]; a2 += hi[0]; a3 += hi[1];
        }
        a0 += __shfl_xor(a0, 16); a1 += __shfl_xor(a1, 16);
        a2 += __shfl_xor(a2, 16); a3 += __shfl_xor(a3, 16);
        a0 += __shfl_xor(a0, 32); a1 += __shfl_xor(a1, 32);
        a2 += __shfl_xor(a2, 32); a3 += __shfl_xor(a3, 32);
        if (lane < 16) {
            uint2 o;
            o.x = (uint)f2bf(a0 * inv) | ((uint)f2bf(a1 * inv) << 16);
            o.y = (uint)f2bf(a2 * inv) | ((uint)f2bf(a3 * inv) << 16);
            *(uint2*)(mean + (size_t)node * 64 + c16 * 4) = o;
        }
    }
}

// ---------- MFMA dense: out = A@W0^T (+ A1@W1^T) [+bias] [+add] [+relu] ----------
// OMODE: 0=bf16, 1=f32, 2=bf16+fp8copy, 3=fp8 only.
template<int OD, bool DUAL, bool HAS_ADD, bool RELU, int OMODE, bool A0F32>
__global__ __launch_bounds__(256) void k_mm(const void* __restrict__ A0,
                                            const ushort* __restrict__ A1,
                                            const ushort* __restrict__ W0,
                                            const ushort* __restrict__ W1,
                                            const float* __restrict__ bias,
                                            const ushort* __restrict__ add,
                                            void* __restrict__ outp,
                                            uchar* __restrict__ f8out, int N) {
    constexpr int NK    = DUAL ? 4 : 2;
    constexpr int M_REP = (OD == 128) ? 4 : 2;
    constexpr int N_REP = 4;
    constexpr int WROWS = M_REP * 16;

    __shared__ __align__(16) ushort sA[128 * 64];
    __shared__ __align__(16) ushort sW[OD * 64];

    const int t    = threadIdx.x;
    const int wid  = t >> 6;
    const int lane = t & 63;
    const int l15  = lane & 15;
    const int lhi  = lane >> 4;
    const int r0   = blockIdx.x * 128;

    int wm, wn0;
    if (OD == 128) { wm = wid >> 1; wn0 = (wid & 1) * 64; }
    else           { wm = wid;      wn0 = 0; }

    f32x4 zero = {0.f, 0.f, 0.f, 0.f};
    f32x4 acc[M_REP][N_REP];
    #pragma unroll
    for (int m = 0; m < M_REP; ++m)
        #pragma unroll
        for (int n = 0; n < N_REP; ++n) acc[m][n] = zero;

    const ushort* A0b = (const ushort*)A0;
    const float*  A0f = (const float*)A0;

    for (int kc = 0; kc < NK; ++kc) {
        const ushort* Ws = (DUAL && kc >= 2) ? W1 : W0;
        const ushort* As = (DUAL && kc >= 2) ? A1 : A0b;
        const int kloc = (kc & 1) * 64;

        __syncthreads();
        // stage A tile: 128 rows x 64 k
        #pragma unroll
        for (int it = 0; it < 4; ++it) {
            int slot = it * 256 + t;
            int row = slot >> 3, k8 = slot & 7;
            int gr = r0 + row; if (gr >= N) gr = N - 1;
            short8 v;
            if constexpr (A0F32) {
                float4 p = *(const float4*)(A0f + (size_t)gr * 128 + kloc + k8 * 8);
                float4 q = *(const float4*)(A0f + (size_t)gr * 128 + kloc + k8 * 8 + 4);
                v[0] = (short)f2bf(p.x); v[1] = (short)f2bf(p.y);
                v[2] = (short)f2bf(p.z); v[3] = (short)f2bf(p.w);
                v[4] = (short)f2bf(q.x); v[5] = (short)f2bf(q.y);
                v[6] = (short)f2bf(q.z); v[7] = (short)f2bf(q.w);
            } else {
                v = *(const short8*)(As + (size_t)gr * 128 + kloc + k8 * 8);
            }
            *(short8*)((char*)sA + ((row * 128 + k8 * 16) ^ ((row & 7) << 4))) = v;
        }
        // stage W tile: OD rows x 64 k
        #pragma unroll
        for (int it = 0; it < OD / 32; ++it) {
            int slot = it * 256 + t;
            int row = slot >> 3, k8 = slot & 7;
            short8 v = *(const short8*)(Ws + (size_t)row * 128 + kloc + k8 * 8);
            *(short8*)((char*)sW + ((row * 128 + k8 * 16) ^ ((row & 7) << 4))) = v;
        }
        __syncthreads();

        #pragma unroll
        for (int kb = 0; kb < 2; ++kb) {
            short8 af[M_REP], bfr[N_REP];
            #pragma unroll
            for (int m = 0; m < M_REP; ++m) {
                int row = wm * WROWS + m * 16 + l15;
                af[m] = *(const short8*)((const char*)sA +
                        ((row * 128 + kb * 64 + lhi * 16) ^ ((row & 7) << 4)));
            }
            #pragma unroll
            for (int n = 0; n < N_REP; ++n) {
                int colr = wn0 + n * 16 + l15;
                bfr[n] = *(const short8*)((const char*)sW +
                         ((colr * 128 + kb * 64 + lhi * 16) ^ ((colr & 7) << 4)));
            }
            #pragma unroll
            for (int m = 0; m < M_REP; ++m)
                #pragma unroll
                for (int n = 0; n < N_REP; ++n)
                    acc[m][n] = __builtin_amdgcn_mfma_f32_16x16x32_bf16(af[m], bfr[n], acc[m][n], 0, 0, 0);
        }
    }

    float bv[N_REP];
    #pragma unroll
    for (int n = 0; n < N_REP; ++n) bv[n] = bias ? bias[wn0 + n * 16 + l15] : 0.f;

    #pragma unroll
    for (int m = 0; m < M_REP; ++m) {
        #pragma unroll
        for (int r = 0; r < 4; ++r) {
            int grow = r0 + wm * WROWS + m * 16 + lhi * 4 + r;
            if (grow < N) {
                #pragma unroll
                for (int n = 0; n < N_REP; ++n) {
                    int colr = wn0 + n * 16 + l15;
                    float v = acc[m][n][r] + bv[n];
                    if (HAS_ADD) v += bf2f(add[(size_t)grow * OD + colr]);
                    if (RELU) v = fmaxf(v, 0.f);
                    if constexpr (OMODE == 1)
                        ((float*)outp)[(size_t)grow * OD + colr] = v;
                    else if constexpr (OMODE != 3)
                        ((ushort*)outp)[(size_t)grow * OD + colr] = f2bf(v);
                    if constexpr (OMODE == 2 || OMODE == 3)
                        f8out[(size_t)grow * OD + colr] = f2e4m3(v);
                }
            }
        }
    }
}

extern "C" void kernel_launch(void* const* d_in, const int* in_sizes, int n_in,
                              void* d_out, int out_size, void* d_ws, size_t ws_size,
                              hipStream_t stream) {
    const float* x     = (const float*)d_in[0];
    const int*   eidx  = (const int*)d_in[1];
    const float* emb_W = (const float*)d_in[2];
    const float* emb_b = (const float*)d_in[3];
    const float* Wl0   = (const float*)d_in[4];
    const float* bl0   = (const float*)d_in[5];
    const float* Wr0   = (const float*)d_in[6];
    const float* Wl1   = (const float*)d_in[7];
    const float* bl1   = (const float*)d_in[8];
    const float* Wr1   = (const float*)d_in[9];
    const float* Wl2   = (const float*)d_in[10];
    const float* bl2   = (const float*)d_in[11];
    const float* Wr2   = (const float*)d_in[12];

    const int N = in_sizes[0] / NODE_D;
    const int E = in_sizes[1] / 2;
    const int* src = eidx;
    const int* dst = eidx + E;
    const int NC = (E + ECHUNK - 1) / ECHUNK;
    const int psz = (N + NPART - 1) / NPART;

    // ---- workspace layout ----
    char* w = (char*)d_ws;
    ushort* h_bf    = (ushort*)w; w += (size_t)N * 128 * sizeof(ushort);
    ushort* mean_bf = (ushort*)w; w += (size_t)N * 128 * sizeof(ushort);
    ushort* wbf     = (ushort*)w; w += (size_t)98304 * sizeof(ushort);
    uint2* ebuf     = (uint2*)w;  w += (size_t)E * sizeof(uint2);
    int* deg    = (int*)w; w += (size_t)N * sizeof(int);
    int* rowptr = (int*)w; w += (size_t)(N + 1) * sizeof(int);
    int* cursor = (int*)w; w += (size_t)N * sizeof(int);
    int* bsums  = (int*)w; w += (size_t)256 * sizeof(int);
    int* cm     = (int*)w; w += (size_t)NC * NPART * sizeof(int);
    int* om     = (int*)w; w += (size_t)NC * NPART * sizeof(int);
    int* pbase  = (int*)w; w += (size_t)(NPART + 1) * sizeof(int);
    int* col    = (int*)w; w += (size_t)E * sizeof(int);

    // fp8 activation copy aliases ebuf (dead after k_fillq; N*128 == E*8 bytes here)
    uchar* h_q8 = (uchar*)ebuf;
    // layer-2 buffers carved from mean_bf region: ga bf16 [N][64], g2 fp8 [N][64]
    ushort* ga = mean_bf;
    uchar*  g2_q8 = (uchar*)(mean_bf + (size_t)N * 64);

    const ushort* embB = wbf;
    const ushort* Wl0B = wbf + 16384;
    const ushort* Wr0B = wbf + 32768;
    const ushort* Wl1B = wbf + 49152;
    const ushort* Wr1B = wbf + 65536;
    const ushort* Wl2B = wbf + 81920;
    const ushort* Wr2B = wbf + 90112;

    const int TPB = 256;

    // ---- CSR build + weight cvt (fused) ----
    hipMemsetAsync(deg, 0, (size_t)N * sizeof(int), stream);
    hipLaunchKernelGGL(k_pre, dim3(NC + 384), dim3(TPB), 0, stream,
                       dst, deg, cm, E, psz, NC,
                       emb_W, Wl0, Wr0, Wl1, Wr1, Wl2, Wr2, wbf);
    const int NB = (N + SCAN_T * SCAN_I - 1) / (SCAN_T * SCAN_I);
    hipLaunchKernelGGL(k_scan_bsum, dim3(NB), dim3(SCAN_T), 0, stream, deg, bsums, N);
    hipLaunchKernelGGL(k_scan_mid, dim3(2), dim3(TPB), 0, stream,
                       bsums, NB, rowptr + N, cm, om, pbase, NC);
    hipLaunchKernelGGL(k_scan_final, dim3(NB), dim3(SCAN_T), 0, stream, deg, bsums, rowptr, cursor, N);
    hipLaunchKernelGGL(k_scatter2, dim3(NC), dim3(TPB), 0, stream, src, dst, om, ebuf, E, psz);
    hipLaunchKernelGGL(k_fillq, dim3(512), dim3(TPB), 0, stream, ebuf, pbase, cursor, col);

    const int dgrid = (N + 127) / 128;
    const int agrid = (N + 3) / 4;

    // ---- embedding: h = x @ emb_W.T + emb_b (writes bf16 + fp8 copy) ----
    hipLaunchKernelGGL((k_mm<128, false, false, false, 2, true>), dim3(dgrid), dim3(TPB), 0, stream,
                       (const void*)x, (const ushort*)nullptr, embB, (const ushort*)nullptr,
                       emb_b, (const ushort*)nullptr, h_bf, h_q8, N);

    // ---- layer 0: h = relu(mean@Wl0.T + bl0 + h@Wr0.T) (writes bf16 + fp8) ----
    hipLaunchKernelGGL((k_aggf<128>), dim3(agrid), dim3(TPB), 0, stream, h_q8, rowptr, col, mean_bf, N);
    hipLaunchKernelGGL((k_mm<128, true, false, true, 2, false>), dim3(dgrid), dim3(TPB), 0, stream,
                       (const void*)mean_bf, h_bf, Wl0B, Wr0B, bl0, (const ushort*)nullptr,
                       h_bf, h_q8, N);

    // ---- layer 1 (bf16 out only) ----
    hipLaunchKernelGGL((k_aggf<128>), dim3(agrid), dim3(TPB), 0, stream, h_q8, rowptr, col, mean_bf, N);
    hipLaunchKernelGGL((k_mm<128, true, false, true, 0, false>), dim3(dgrid), dim3(TPB), 0, stream,
                       (const void*)mean_bf, h_bf, Wl1B, Wr1B, bl1, (const ushort*)nullptr,
                       h_bf, (uchar*)nullptr, N);

    // ---- layer 2: pre-transform to fp8 (linearity), aggregate 64-dim, root + add ----
    hipLaunchKernelGGL((k_mm<64, false, false, false, 3, false>), dim3(dgrid), dim3(TPB), 0, stream,
                       (const void*)h_bf, (const ushort*)nullptr, Wl2B, (const ushort*)nullptr,
                       (const float*)nullptr, (const ushort*)nullptr, (void*)nullptr, g2_q8, N);
    hipLaunchKernelGGL((k_aggf<64>), dim3(agrid), dim3(TPB), 0, stream, g2_q8, rowptr, col, ga, N);
    hipLaunchKernelGGL((k_mm<64, false, true, false, 1, false>), dim3(dgrid), dim3(TPB), 0, stream,
                       (const void*)h_bf, (const ushort*)nullptr, Wr2B, (const ushort*)nullptr,
                       bl2, ga, d_out, (uchar*)nullptr, N);
}

// Round 9
// 358.868 us; speedup vs baseline: 1.2821x; 1.1875x over previous
//
#include <hip/hip_runtime.h>

typedef __attribute__((ext_vector_type(8))) short short8;
typedef __attribute__((ext_vector_type(4))) float f32x4;
typedef __attribute__((ext_vector_type(2))) float f32x2;

#define NODE_D 128
#define ECH 16384          // edges per counting/scatter chunk
#define PSH 9              // partition = 512 consecutive dst nodes (power of 2)
// NOTE: pipeline assumes N <= 131072 (src packs into 17 bits; NP <= 256)

__device__ __forceinline__ float bf2f(ushort u) {
    union { uint i; float f; } c; c.i = ((uint)u) << 16; return c.f;
}
__device__ __forceinline__ ushort f2bf(float f) {
    union { float f; uint i; } c; c.f = f;
    return (ushort)((c.i + 0x7FFF + ((c.i >> 16) & 1)) >> 16);
}
__device__ __forceinline__ uchar f2e4m3(float f) {
    uint w = (uint)__builtin_amdgcn_cvt_pk_fp8_f32(f, f, 0, false);
    return (uchar)(w & 0xff);
}

// ---------- fused: per-chunk partition histogram (blocks 0..NC) + weight cvt ----------
__global__ __launch_bounds__(256) void k_count(const int* __restrict__ dst,
                                               int* __restrict__ cm,
                                               int E, int NC,
                                               const float* __restrict__ s0, const float* __restrict__ s1,
                                               const float* __restrict__ s2, const float* __restrict__ s3,
                                               const float* __restrict__ s4, const float* __restrict__ s5,
                                               const float* __restrict__ s6, ushort* __restrict__ wdst) {
    if ((int)blockIdx.x >= NC) {
        int i = ((int)blockIdx.x - NC) * 256 + threadIdx.x;
        if (i >= 98304) return;
        const float* s; int off;
        if (i < 16384)      { s = s0; off = i; }
        else if (i < 32768) { s = s1; off = i - 16384; }
        else if (i < 49152) { s = s2; off = i - 32768; }
        else if (i < 65536) { s = s3; off = i - 49152; }
        else if (i < 81920) { s = s4; off = i - 65536; }
        else if (i < 90112) { s = s5; off = i - 81920; }
        else                { s = s6; off = i - 90112; }
        wdst[i] = f2bf(s[off]);
        return;
    }
    __shared__ int lh[256];
    lh[threadIdx.x] = 0;
    __syncthreads();
    int c = blockIdx.x;
    int lo = c * ECH, hi = min(lo + ECH, E);
    for (int i = lo + (int)threadIdx.x; i < hi; i += 256)
        atomicAdd(&lh[dst[i] >> PSH], 1);
    __syncthreads();
    cm[c * 256 + threadIdx.x] = lh[threadIdx.x];
}

// ---------- single block: partition-major scan of cm -> om, pbase; rowptr[N]=E ----------
__global__ __launch_bounds__(256) void k_pscan(const int* __restrict__ cm,
                                               int* __restrict__ om,
                                               int* __restrict__ pbase,
                                               int* __restrict__ rowptrN,
                                               int NC, int NP, int E) {
    __shared__ int ts[256];
    int p = threadIdx.x;
    int s = 0;
    if (p < NP)
        for (int c = 0; c < NC; ++c) s += cm[c * 256 + p];
    ts[p] = s;
    __syncthreads();
    for (int st = 1; st < 256; st <<= 1) {
        int add = (p >= st) ? ts[p - st] : 0;
        __syncthreads();
        ts[p] += add;
        __syncthreads();
    }
    int base = ts[p] - s;   // exclusive
    if (p < NP) {
        int run = base;
        for (int c = 0; c < NC; ++c) {
            om[c * 256 + p] = run;
            run += cm[c * 256 + p];
        }
        pbase[p] = base;
    }
    if (p == 0) { pbase[NP] = E; rowptrN[0] = E; }
}

// ---------- deterministic scatter: edges -> partition-major packed ebuf (no global atomics) ----------
// packed: bits 0-16 = src, bits 17-25 = local node (d & 511)
__global__ __launch_bounds__(256) void k_scatter3(const int* __restrict__ src,
                                                  const int* __restrict__ dst,
                                                  const int* __restrict__ om,
                                                  uint* __restrict__ ebuf, int E) {
    __shared__ int cur[256];
    int c = blockIdx.x;
    cur[threadIdx.x] = om[c * 256 + threadIdx.x];
    __syncthreads();
    int lo = c * ECH, hi = min(lo + ECH, E);
    for (int i = lo + (int)threadIdx.x; i < hi; i += 256) {
        int d = dst[i];
        int pos = atomicAdd(&cur[d >> PSH], 1);
        ebuf[pos] = ((uint)(d & 511) << 17) | (uint)src[i];
    }
}

// ---------- per-partition local CSR: LDS hist -> LDS scan -> rowptr + col ----------
__global__ __launch_bounds__(256) void k_local(const uint* __restrict__ ebuf,
                                               const int* __restrict__ pbase,
                                               int* __restrict__ rowptr,
                                               int* __restrict__ col, int N) {
    __shared__ int hist[512];
    __shared__ int cur[512];
    __shared__ int ts[256];
    int p = blockIdx.x;
    int t = threadIdx.x;
    int lo = pbase[p], hi = pbase[p + 1];
    hist[t] = 0; hist[t + 256] = 0;
    __syncthreads();
    for (int j = lo + t; j < hi; j += 256)
        atomicAdd(&hist[ebuf[j] >> 17], 1);
    __syncthreads();
    int v0 = hist[2 * t], v1 = hist[2 * t + 1];
    int s = v0 + v1;
    ts[t] = s;
    __syncthreads();
    for (int st = 1; st < 256; st <<= 1) {
        int add = (t >= st) ? ts[t - st] : 0;
        __syncthreads();
        ts[t] += add;
        __syncthreads();
    }
    int excl = ts[t] - s + lo;
    int node0 = (p << PSH) + 2 * t;
    if (node0 < N) rowptr[node0] = excl;
    if (node0 + 1 < N) rowptr[node0 + 1] = excl + v0;
    cur[2 * t] = excl;
    cur[2 * t + 1] = excl + v0;
    __syncthreads();
    for (int j = lo + t; j < hi; j += 256) {
        uint e = ebuf[j];
        int pos = atomicAdd(&cur[e >> 17], 1);
        col[pos] = (int)(e & 0x1FFFF);
    }
}

// ---------- mean aggregation over fp8(e4m3) activations -> bf16 mean ----------
template<int D>
__global__ __launch_bounds__(256) void k_aggf(const uchar* __restrict__ hq,
                                              const int* __restrict__ rowptr,
                                              const int* __restrict__ col,
                                              ushort* __restrict__ mean, int N) {
    int node = blockIdx.x * 4 + (threadIdx.x >> 6);
    if (node >= N) return;
    int lane = threadIdx.x & 63;
    int beg = rowptr[node];
    int end = rowptr[node + 1];
    float inv = 1.f / fmaxf((float)(end - beg), 1.f);

    if constexpr (D == 128) {
        int half = lane >> 5;
        int l32  = lane & 31;
        const uchar* base = hq + l32 * 4;
        float a0 = 0.f, a1 = 0.f, a2 = 0.f, a3 = 0.f;
        int jb = beg;
        for (; jb + 15 < end; jb += 16) {
            uint v[8];
            #pragma unroll
            for (int q = 0; q < 8; ++q) {
                int s = col[jb + half * 8 + q];
                v[q] = *(const uint*)(base + (size_t)s * 128);
            }
            #pragma unroll
            for (int q = 0; q < 8; ++q) {
                f32x2 lo = __builtin_amdgcn_cvt_pk_f32_fp8(v[q], false);
                f32x2 hi = __builtin_amdgcn_cvt_pk_f32_fp8(v[q], true);
                a0 += lo[0]; a1 += lo[1]; a2 += hi[0]; a3 += hi[1];
            }
        }
        for (; jb + 1 < end; jb += 2) {
            uint v = *(const uint*)(base + (size_t)col[jb + half] * 128);
            f32x2 lo = __builtin_amdgcn_cvt_pk_f32_fp8(v, false);
            f32x2 hi = __builtin_amdgcn_cvt_pk_f32_fp8(v, true);
            a0 += lo[0]; a1 += lo[1]; a2 += hi[0]; a3 += hi[1];
        }
        if (jb < end && half == 0) {
            uint v = *(const uint*)(base + (size_t)col[jb] * 128);
            f32x2 lo = __builtin_amdgcn_cvt_pk_f32_fp8(v, false);
            f32x2 hi = __builtin_amdgcn_cvt_pk_f32_fp8(v, true);
            a0 += lo[0]; a1 += lo[1]; a2 += hi[0]; a3 += hi[1];
        }
        a0 += __shfl_xor(a0, 32); a1 += __shfl_xor(a1, 32);
        a2 += __shfl_xor(a2, 32); a3 += __shfl_xor(a3, 32);
        if (half == 0) {
            uint2 o;
            o.x = (uint)f2bf(a0 * inv) | ((uint)f2bf(a1 * inv) << 16);
            o.y = (uint)f2bf(a2 * inv) | ((uint)f2bf(a3 * inv) << 16);
            *(uint2*)(mean + (size_t)node * 128 + l32 * 4) = o;
        }
    } else {
        int g   = lane >> 4;
        int c16 = lane & 15;
        const uchar* base = hq + c16 * 4;
        float a0 = 0.f, a1 = 0.f, a2 = 0.f, a3 = 0.f;
        int jb = beg;
        for (; jb + 31 < end; jb += 32) {
            uint v[8];
            #pragma unroll
            for (int q = 0; q < 8; ++q) {
                int s = col[jb + g * 8 + q];
                v[q] = *(const uint*)(base + (size_t)s * 64);
            }
            #pragma unroll
            for (int q = 0; q < 8; ++q) {
                f32x2 lo = __builtin_amdgcn_cvt_pk_f32_fp8(v[q], false);
                f32x2 hi = __builtin_amdgcn_cvt_pk_f32_fp8(v[q], true);
                a0 += lo[0]; a1 += lo[1]; a2 += hi[0]; a3 += hi[1];
            }
        }
        for (; jb + 3 < end; jb += 4) {
            uint v = *(const uint*)(base + (size_t)col[jb + g] * 64);
            f32x2 lo = __builtin_amdgcn_cvt_pk_f32_fp8(v, false);
            f32x2 hi = __builtin_amdgcn_cvt_pk_f32_fp8(v, true);
            a0 += lo[0]; a1 += lo[1]; a2 += hi[0]; a3 += hi[1];
        }
        int rem = end - jb;
        if (g < rem) {
            uint v = *(const uint*)(base + (size_t)col[jb + g] * 64);
            f32x2 lo = __builtin_amdgcn_cvt_pk_f32_fp8(v, false);
            f32x2 hi = __builtin_amdgcn_cvt_pk_f32_fp8(v, true);
            a0 += lo[0]; a1 += lo[1]; a2 += hi[0]; a3 += hi[1];
        }
        a0 += __shfl_xor(a0, 16); a1 += __shfl_xor(a1, 16);
        a2 += __shfl_xor(a2, 16); a3 += __shfl_xor(a3, 16);
        a0 += __shfl_xor(a0, 32); a1 += __shfl_xor(a1, 32);
        a2 += __shfl_xor(a2, 32); a3 += __shfl_xor(a3, 32);
        if (lane < 16) {
            uint2 o;
            o.x = (uint)f2bf(a0 * inv) | ((uint)f2bf(a1 * inv) << 16);
            o.y = (uint)f2bf(a2 * inv) | ((uint)f2bf(a3 * inv) << 16);
            *(uint2*)(mean + (size_t)node * 64 + c16 * 4) = o;
        }
    }
}

// ---------- MFMA dense: out = A@W0^T (+ A1@W1^T) [+bias] [+add] [+relu] ----------
// OMODE: 0=bf16, 1=f32, 2=bf16+fp8copy, 3=fp8 only.
template<int OD, bool DUAL, bool HAS_ADD, bool RELU, int OMODE, bool A0F32>
__global__ __launch_bounds__(256) void k_mm(const void* __restrict__ A0,
                                            const ushort* __restrict__ A1,
                                            const ushort* __restrict__ W0,
                                            const ushort* __restrict__ W1,
                                            const float* __restrict__ bias,
                                            const ushort* __restrict__ add,
                                            void* __restrict__ outp,
                                            uchar* __restrict__ f8out, int N) {
    constexpr int NK    = DUAL ? 4 : 2;
    constexpr int M_REP = (OD == 128) ? 4 : 2;
    constexpr int N_REP = 4;
    constexpr int WROWS = M_REP * 16;

    __shared__ __align__(16) ushort sA[128 * 64];
    __shared__ __align__(16) ushort sW[OD * 64];

    const int t    = threadIdx.x;
    const int wid  = t >> 6;
    const int lane = t & 63;
    const int l15  = lane & 15;
    const int lhi  = lane >> 4;
    const int r0   = blockIdx.x * 128;

    int wm, wn0;
    if (OD == 128) { wm = wid >> 1; wn0 = (wid & 1) * 64; }
    else           { wm = wid;      wn0 = 0; }

    f32x4 zero = {0.f, 0.f, 0.f, 0.f};
    f32x4 acc[M_REP][N_REP];
    #pragma unroll
    for (int m = 0; m < M_REP; ++m)
        #pragma unroll
        for (int n = 0; n < N_REP; ++n) acc[m][n] = zero;

    const ushort* A0b = (const ushort*)A0;
    const float*  A0f = (const float*)A0;

    for (int kc = 0; kc < NK; ++kc) {
        const ushort* Ws = (DUAL && kc >= 2) ? W1 : W0;
        const ushort* As = (DUAL && kc >= 2) ? A1 : A0b;
        const int kloc = (kc & 1) * 64;

        __syncthreads();
        // stage A tile: 128 rows x 64 k
        #pragma unroll
        for (int it = 0; it < 4; ++it) {
            int slot = it * 256 + t;
            int row = slot >> 3, k8 = slot & 7;
            int gr = r0 + row; if (gr >= N) gr = N - 1;
            short8 v;
            if constexpr (A0F32) {
                float4 p = *(const float4*)(A0f + (size_t)gr * 128 + kloc + k8 * 8);
                float4 q = *(const float4*)(A0f + (size_t)gr * 128 + kloc + k8 * 8 + 4);
                v[0] = (short)f2bf(p.x); v[1] = (short)f2bf(p.y);
                v[2] = (short)f2bf(p.z); v[3] = (short)f2bf(p.w);
                v[4] = (short)f2bf(q.x); v[5] = (short)f2bf(q.y);
                v[6] = (short)f2bf(q.z); v[7] = (short)f2bf(q.w);
            } else {
                v = *(const short8*)(As + (size_t)gr * 128 + kloc + k8 * 8);
            }
            *(short8*)((char*)sA + ((row * 128 + k8 * 16) ^ ((row & 7) << 4))) = v;
        }
        // stage W tile: OD rows x 64 k
        #pragma unroll
        for (int it = 0; it < OD / 32; ++it) {
            int slot = it * 256 + t;
            int row = slot >> 3, k8 = slot & 7;
            short8 v = *(const short8*)(Ws + (size_t)row * 128 + kloc + k8 * 8);
            *(short8*)((char*)sW + ((row * 128 + k8 * 16) ^ ((row & 7) << 4))) = v;
        }
        __syncthreads();

        #pragma unroll
        for (int kb = 0; kb < 2; ++kb) {
            short8 af[M_REP], bfr[N_REP];
            #pragma unroll
            for (int m = 0; m < M_REP; ++m) {
                int row = wm * WROWS + m * 16 + l15;
                af[m] = *(const short8*)((const char*)sA +
                        ((row * 128 + kb * 64 + lhi * 16) ^ ((row & 7) << 4)));
            }
            #pragma unroll
            for (int n = 0; n < N_REP; ++n) {
                int colr = wn0 + n * 16 + l15;
                bfr[n] = *(const short8*)((const char*)sW +
                         ((colr * 128 + kb * 64 + lhi * 16) ^ ((colr & 7) << 4)));
            }
            #pragma unroll
            for (int m = 0; m < M_REP; ++m)
                #pragma unroll
                for (int n = 0; n < N_REP; ++n)
                    acc[m][n] = __builtin_amdgcn_mfma_f32_16x16x32_bf16(af[m], bfr[n], acc[m][n], 0, 0, 0);
        }
    }

    float bv[N_REP];
    #pragma unroll
    for (int n = 0; n < N_REP; ++n) bv[n] = bias ? bias[wn0 + n * 16 + l15] : 0.f;

    #pragma unroll
    for (int m = 0; m < M_REP; ++m) {
        #pragma unroll
        for (int r = 0; r < 4; ++r) {
            int grow = r0 + wm * WROWS + m * 16 + lhi * 4 + r;
            if (grow < N) {
                #pragma unroll
                for (int n = 0; n < N_REP; ++n) {
                    int colr = wn0 + n * 16 + l15;
                    float v = acc[m][n][r] + bv[n];
                    if (HAS_ADD) v += bf2f(add[(size_t)grow * OD + colr]);
                    if (RELU) v = fmaxf(v, 0.f);
                    if constexpr (OMODE == 1)
                        ((float*)outp)[(size_t)grow * OD + colr] = v;
                    else if constexpr (OMODE != 3)
                        ((ushort*)outp)[(size_t)grow * OD + colr] = f2bf(v);
                    if constexpr (OMODE == 2 || OMODE == 3)
                        f8out[(size_t)grow * OD + colr] = f2e4m3(v);
                }
            }
        }
    }
}

extern "C" void kernel_launch(void* const* d_in, const int* in_sizes, int n_in,
                              void* d_out, int out_size, void* d_ws, size_t ws_size,
                              hipStream_t stream) {
    const float* x     = (const float*)d_in[0];
    const int*   eidx  = (const int*)d_in[1];
    const float* emb_W = (const float*)d_in[2];
    const float* emb_b = (const float*)d_in[3];
    const float* Wl0   = (const float*)d_in[4];
    const float* bl0   = (const float*)d_in[5];
    const float* Wr0   = (const float*)d_in[6];
    const float* Wl1   = (const float*)d_in[7];
    const float* bl1   = (const float*)d_in[8];
    const float* Wr1   = (const float*)d_in[9];
    const float* Wl2   = (const float*)d_in[10];
    const float* bl2   = (const float*)d_in[11];
    const float* Wr2   = (const float*)d_in[12];

    const int N = in_sizes[0] / NODE_D;
    const int E = in_sizes[1] / 2;
    const int* src = eidx;
    const int* dst = eidx + E;
    const int NC = (E + ECH - 1) / ECH;           // 98 chunks
    const int NP = (N + (1 << PSH) - 1) >> PSH;   // 196 partitions

    // ---- workspace layout ----
    char* w = (char*)d_ws;
    ushort* h_bf    = (ushort*)w; w += (size_t)N * 128 * sizeof(ushort);
    ushort* mean_bf = (ushort*)w; w += (size_t)N * 128 * sizeof(ushort);
    ushort* wbf     = (ushort*)w; w += (size_t)98304 * sizeof(ushort);
    uchar* h_q8     = (uchar*)w;  w += (size_t)N * 128;
    uint* ebuf      = (uint*)w;   w += (size_t)E * sizeof(uint);
    int* cm     = (int*)w; w += (size_t)NC * 256 * sizeof(int);
    int* om     = (int*)w; w += (size_t)NC * 256 * sizeof(int);
    int* pbase  = (int*)w; w += (size_t)(NP + 1) * sizeof(int);
    int* rowptr = (int*)w; w += (size_t)(N + 1) * sizeof(int);
    int* col    = (int*)w; w += (size_t)E * sizeof(int);

    // layer-2 buffers carved from mean_bf region: ga bf16 [N][64], g2 fp8 [N][64]
    ushort* ga = mean_bf;
    uchar*  g2_q8 = (uchar*)(mean_bf + (size_t)N * 64);

    const ushort* embB = wbf;
    const ushort* Wl0B = wbf + 16384;
    const ushort* Wr0B = wbf + 32768;
    const ushort* Wl1B = wbf + 49152;
    const ushort* Wr1B = wbf + 65536;
    const ushort* Wl2B = wbf + 81920;
    const ushort* Wr2B = wbf + 90112;

    const int TPB = 256;

    // ---- CSR build: count -> pscan -> deterministic scatter -> per-partition local sort ----
    hipLaunchKernelGGL(k_count, dim3(NC + 384), dim3(TPB), 0, stream,
                       dst, cm, E, NC, emb_W, Wl0, Wr0, Wl1, Wr1, Wl2, Wr2, wbf);
    hipLaunchKernelGGL(k_pscan, dim3(1), dim3(TPB), 0, stream,
                       cm, om, pbase, rowptr + N, NC, NP, E);
    hipLaunchKernelGGL(k_scatter3, dim3(NC), dim3(TPB), 0, stream, src, dst, om, ebuf, E);
    hipLaunchKernelGGL(k_local, dim3(NP), dim3(TPB), 0, stream, ebuf, pbase, rowptr, col, N);

    const int dgrid = (N + 127) / 128;
    const int agrid = (N + 3) / 4;

    // ---- embedding: h = x @ emb_W.T + emb_b (writes bf16 + fp8 copy) ----
    hipLaunchKernelGGL((k_mm<128, false, false, false, 2, true>), dim3(dgrid), dim3(TPB), 0, stream,
                       (const void*)x, (const ushort*)nullptr, embB, (const ushort*)nullptr,
                       emb_b, (const ushort*)nullptr, h_bf, h_q8, N);

    // ---- layer 0: h = relu(mean@Wl0.T + bl0 + h@Wr0.T) (writes bf16 + fp8) ----
    hipLaunchKernelGGL((k_aggf<128>), dim3(agrid), dim3(TPB), 0, stream, h_q8, rowptr, col, mean_bf, N);
    hipLaunchKernelGGL((k_mm<128, true, false, true, 2, false>), dim3(dgrid), dim3(TPB), 0, stream,
                       (const void*)mean_bf, h_bf, Wl0B, Wr0B, bl0, (const ushort*)nullptr,
                       h_bf, h_q8, N);

    // ---- layer 1 (bf16 out only) ----
    hipLaunchKernelGGL((k_aggf<128>), dim3(agrid), dim3(TPB), 0, stream, h_q8, rowptr, col, mean_bf, N);
    hipLaunchKernelGGL((k_mm<128, true, false, true, 0, false>), dim3(dgrid), dim3(TPB), 0, stream,
                       (const void*)mean_bf, h_bf, Wl1B, Wr1B, bl1, (const ushort*)nullptr,
                       h_bf, (uchar*)nullptr, N);

    // ---- layer 2: pre-transform to fp8 (linearity), aggregate 64-dim, root + add ----
    hipLaunchKernelGGL((k_mm<64, false, false, false, 3, false>), dim3(dgrid), dim3(TPB), 0, stream,
                       (const void*)h_bf, (const ushort*)nullptr, Wl2B, (const ushort*)nullptr,
                       (const float*)nullptr, (const ushort*)nullptr, (void*)nullptr, g2_q8, N);
    hipLaunchKernelGGL((k_aggf<64>), dim3(agrid), dim3(TPB), 0, stream, g2_q8, rowptr, col, ga, N);
    hipLaunchKernelGGL((k_mm<64, false, true, false, 1, false>), dim3(dgrid), dim3(TPB), 0, stream,
                       (const void*)h_bf, (const ushort*)nullptr, Wr2B, (const ushort*)nullptr,
                       bl2, ga, d_out, (uchar*)nullptr, N);
}